// Round 1
// baseline (572.837 us; speedup 1.0000x reference)
//
#include <hip/hip_runtime.h>
#include <cmath>

// ---------------------------------------------------------------------------
// Problem: out = x @ dequant(qweight, meta, scale)
//   x      : fp32 [M,K]  (reference fp16 realized as fp32 on device)
//   qweight: int32 [K,N] in [0,16);  meta: int32 [K/4,N] in [0,6)
//   scale  : fp32 [K/128,N];  out: fp32 [M,N]
// Pipeline: convert x->bf16, dequant W -> bf16 Wt[NC][K] (chunked), then GEMM.
// R6: GEMM upgraded from m97-class 128^2/2-barrier structure (~520 TF here)
// to the 256^2 8-phase template (T1 XCD swizzle + T2 LDS XOR swizzle +
// T3/T4 8-phase counted vmcnt + T5 setprio). Derived wait for this stage
// schedule: vmcnt(4) at phases 4 and 8 only.
// ---------------------------------------------------------------------------

typedef __attribute__((ext_vector_type(8))) short bf16x8;
typedef __attribute__((ext_vector_type(4))) float f32x4;

__device__ inline unsigned short f2bf(float f) {
    union { float f; unsigned u; } v; v.f = f;
    unsigned r = (v.u + 0x7FFFu + ((v.u >> 16) & 1u)) >> 16;  // RNE
    return (unsigned short)r;
}

// ---------------------------------------------------------------------------
// Kernel 0: x fp32 -> bf16, 8 elements/thread, fully coalesced. (unchanged)
// ---------------------------------------------------------------------------
__global__ __launch_bounds__(256) void convert_x(
    const float* __restrict__ x, unsigned short* __restrict__ xb, long long total)
{
    const long long base = ((long long)blockIdx.x * 256 + threadIdx.x) * 8;
    if (base + 8 > total) return;
    const float4 a = *reinterpret_cast<const float4*>(x + base);
    const float4 b = *reinterpret_cast<const float4*>(x + base + 4);
    uint4 o;
    o.x = (unsigned)f2bf(a.x) | ((unsigned)f2bf(a.y) << 16);
    o.y = (unsigned)f2bf(a.z) | ((unsigned)f2bf(a.w) << 16);
    o.z = (unsigned)f2bf(b.x) | ((unsigned)f2bf(b.y) << 16);
    o.w = (unsigned)f2bf(b.z) | ((unsigned)f2bf(b.w) << 16);
    *reinterpret_cast<uint4*>(xb + base) = o;
}

// ---------------------------------------------------------------------------
// Kernel 1: dequant + transpose one N-chunk. Tile = 64(k) x 64(n). (unchanged)
// Pattern LUT nibbles: [1100]->3 [1010]->5 [1001]->9 [0110]->6 [0101]->A
// [0011]->C  => 0xCA6953
// ---------------------------------------------------------------------------
__global__ __launch_bounds__(256) void dequant_wt(
    const int* __restrict__ q, const int* __restrict__ meta,
    const float* __restrict__ scale,
    unsigned short* __restrict__ wt,   // [NC, K] chunk-local, bf16
    int K, int N, int nbase)
{
    __shared__ __align__(16) unsigned short lds[64 * 68];  // [n][k], stride 68
    const int t  = threadIdx.x;
    const int n  = t & 63;
    const int kc = t >> 6;
    const int k0 = blockIdx.x * 64;
    const int nl0 = blockIdx.y * 64;
    const int ng = nbase + nl0 + n;
    const int g = k0 >> 7;
    const float sc = scale[(size_t)g * N + ng];
    const unsigned lut = 0xCA6953u;

    #pragma unroll
    for (int p = 0; p < 4; ++p) {
        const int kl = p * 16 + kc * 4;
        const int kg = k0 + kl;
        const int mv = meta[(size_t)(kg >> 2) * N + ng];
        const unsigned pat = (lut >> (mv * 4)) & 0xFu;
        unsigned short w[4];
        #pragma unroll
        for (int j = 0; j < 4; ++j) {
            const int qv = q[(size_t)(kg + j) * N + ng];
            const float wf = ((pat >> j) & 1u) ? (float)(qv - 8) * sc : 0.0f;
            w[j] = f2bf(wf);
        }
        uint2 pk;
        pk.x = (unsigned)w[0] | ((unsigned)w[1] << 16);
        pk.y = (unsigned)w[2] | ((unsigned)w[3] << 16);
        *reinterpret_cast<uint2*>(&lds[n * 68 + kl]) = pk;
    }
    __syncthreads();
    #pragma unroll
    for (int p = 0; p < 2; ++p) {
        const int idx = p * 256 + t;
        const int nr  = idx >> 3;
        const int ch  = idx & 7;
        const uint2 lo = *reinterpret_cast<const uint2*>(&lds[nr * 68 + ch * 8]);
        const uint2 hi = *reinterpret_cast<const uint2*>(&lds[nr * 68 + ch * 8 + 4]);
        uint4 vv; vv.x = lo.x; vv.y = lo.y; vv.z = hi.x; vv.w = hi.y;
        *reinterpret_cast<uint4*>(&wt[(size_t)(nl0 + nr) * K + k0 + ch * 8]) = vv;
    }
}

// ---------------------------------------------------------------------------
// Kernel 2: 256x256 8-phase GEMM. C[:, nbase+..] += A[M,K] * Bt[NC,K]^T.
// 512 thr = 8 waves (2M x 4N); per-wave 128x64 out; BK=64; 128 KiB LDS
// (2 dbuf x 2 halves x [128][64] bf16 for each of A,B).
// Swizzle: LDS(row,c16B) holds global chunk c^(row&7); DMA dest is linear so
// the GLOBAL source is pre-swizzled (csrc=(l&7)^((l>>3)&7)); ds_reads apply
// chunk' = (kk*4+quad)^(l&7)  -> 2 lanes/bank-group = conflict-free.
// Stage schedule (1 half-tile/phase): P1,P2: A(next tile)->other buf;
// P3,P4: B(T+2)->buf0; P5,P6: A(T+2)->buf0; P7,P8: B(T+3)->buf1.
// Waits: vmcnt(4) at end of P4 and P8 only (2 loads/phase in flight x2).
// ---------------------------------------------------------------------------
#define BAR() do { asm volatile("" ::: "memory"); \
                   __builtin_amdgcn_s_barrier(); \
                   asm volatile("" ::: "memory"); } while (0)

#define GLDS(g, s) __builtin_amdgcn_global_load_lds( \
    (const __attribute__((address_space(1))) void*)(g), \
    (__attribute__((address_space(3))) void*)(s), 16, 0, 0)

#define MFMA(d, x, y) d = __builtin_amdgcn_mfma_f32_16x16x32_bf16(x, y, d, 0, 0, 0)

__global__ __launch_bounds__(512, 2) void gemm256(
    const unsigned short* __restrict__ A,   // bf16 [M,K]
    const unsigned short* __restrict__ Bt,  // bf16 [NC,K] chunk-local
    float* __restrict__ C,                  // fp32 [M,N]
    int M, int N, int K, int nbase)
{
    __shared__ __align__(16) unsigned short As[32768];  // 2buf x 2half x 128 x 64
    __shared__ __align__(16) unsigned short Bs[32768];

    const int t    = threadIdx.x;
    const int w    = t >> 6;
    const int lane = t & 63;
    const int wm   = w >> 2;        // 0..1  (M dir)
    const int wn   = w & 3;         // 0..3  (N dir)
    const int l16  = lane & 15;
    const int quad = lane >> 4;

    // T1: bijective XCD swizzle of the linear block id (m204 formula)
    const int gx = gridDim.x;
    int bid = blockIdx.y * gx + blockIdx.x;
    const int nwg = gx * gridDim.y;
    if (nwg >= 8) {
        const int q8 = nwg >> 3, r8 = nwg & 7;
        const int xcd = bid & 7, off = bid >> 3;
        bid = (xcd < r8 ? xcd * (q8 + 1) : r8 * (q8 + 1) + (xcd - r8) * q8) + off;
    }
    const int n0 = (bid % gx) * 256;   // chunk-local n tile base
    const int m0 = (bid / gx) * 256;

    // staging source bases (pre-swizzled chunk within each 128B row)
    const int    csrc = ((lane & 7) ^ ((lane >> 3) & 7)) * 8;  // elements
    const size_t aB = (size_t)(m0 + w * 8 + (lane >> 3)) * K + csrc;
    const size_t bB = (size_t)(n0 + w * 8 + (lane >> 3)) * K + csrc;
    const size_t J  = (size_t)64 * K;    // issue-1 row offset
    const size_t H  = (size_t)128 * K;   // half row offset
    const int sdst  = w * 512;           // wave-uniform LDS dest (ushort idx)

    // ds_read bases (ushort idx). chunk'(kk) = (kk*4+quad)^(lane&7)
    const int sw0 = ((quad ^ (lane & 7)) * 8);
    const int sw1 = (((4 + quad) ^ (lane & 7)) * 8);
    const int aR  = wm * 8192 + l16 * 64;
    const int bR  = (wn >> 1) * 8192 + ((wn & 1) * 64 + l16) * 64;

    int kA = 0, kB = 0;  // k element offset of next tile to stage

#define STAGE_A(buf, h) do { \
    GLDS(A + aB + (size_t)(h) * H + kA, &As[(buf)*16384 + (h)*8192 + sdst]); \
    GLDS(A + aB + (size_t)(h) * H + J + kA, &As[(buf)*16384 + (h)*8192 + 4096 + sdst]); \
  } while (0)
#define STAGE_B(buf, h) do { \
    GLDS(Bt + bB + (size_t)(h) * H + kB, &Bs[(buf)*16384 + (h)*8192 + sdst]); \
    GLDS(Bt + bB + (size_t)(h) * H + J + kB, &Bs[(buf)*16384 + (h)*8192 + 4096 + sdst]); \
  } while (0)

    f32x4 acc[8][4];
    #pragma unroll
    for (int i = 0; i < 8; ++i)
        #pragma unroll
        for (int j = 0; j < 4; ++j)
            acc[i][j] = (f32x4){0.f, 0.f, 0.f, 0.f};

    // prologue: T0.B -> buf0, T0.A -> buf0, T1.B -> buf1 (6 half-tiles)
    STAGE_B(0, 0); STAGE_B(0, 1); kB += 64;
    STAGE_A(0, 0); STAGE_A(0, 1); kA += 64;
    STAGE_B(1, 0); STAGE_B(1, 1); kB += 64;
    asm volatile("s_waitcnt vmcnt(4)" ::: "memory");  // T0 landed
    BAR();

    bf16x8 a[4][2], b0[2][2], b1[2][2];

    // 4 phases per tile; quadrants (qm,qn) in order (0,0)(0,1)(1,1)(1,0).
    // b0 (qn0) stays live P1->P4 so P4 has zero ds_reads.
#define PHASES(buf, obuf) do { \
  /* P1: read A[qm0]+B[qn0] (12 rds), stage A(next)->obuf h0, mfma q(0,0) */ \
  _Pragma("unroll") for (int i = 0; i < 4; ++i) { \
    a[i][0] = *(const bf16x8*)&As[(buf)*16384 + aR + i*1024 + sw0]; \
    a[i][1] = *(const bf16x8*)&As[(buf)*16384 + aR + i*1024 + sw1]; } \
  _Pragma("unroll") for (int j = 0; j < 2; ++j) { \
    b0[j][0] = *(const bf16x8*)&Bs[(buf)*16384 + bR + j*1024 + sw0]; \
    b0[j][1] = *(const bf16x8*)&Bs[(buf)*16384 + bR + j*1024 + sw1]; } \
  STAGE_A(obuf, 0); \
  BAR(); \
  asm volatile("s_waitcnt lgkmcnt(0)" ::: "memory"); \
  __builtin_amdgcn_s_setprio(1); \
  _Pragma("unroll") for (int i = 0; i < 4; ++i) \
    _Pragma("unroll") for (int j = 0; j < 2; ++j) { \
      MFMA(acc[i][j], a[i][0], b0[j][0]); MFMA(acc[i][j], a[i][1], b0[j][1]); } \
  __builtin_amdgcn_s_setprio(0); \
  BAR(); \
  /* P2: read B[qn1] (4 rds), stage A h1, mfma q(0,1) */ \
  _Pragma("unroll") for (int j = 0; j < 2; ++j) { \
    b1[j][0] = *(const bf16x8*)&Bs[(buf)*16384 + bR + (2+j)*1024 + sw0]; \
    b1[j][1] = *(const bf16x8*)&Bs[(buf)*16384 + bR + (2+j)*1024 + sw1]; } \
  STAGE_A(obuf, 1); kA += 64; if (kA >= K) kA = 0; \
  BAR(); \
  asm volatile("s_waitcnt lgkmcnt(0)" ::: "memory"); \
  __builtin_amdgcn_s_setprio(1); \
  _Pragma("unroll") for (int i = 0; i < 4; ++i) \
    _Pragma("unroll") for (int j = 0; j < 2; ++j) { \
      MFMA(acc[i][2+j], a[i][0], b1[j][0]); MFMA(acc[i][2+j], a[i][1], b1[j][1]); } \
  __builtin_amdgcn_s_setprio(0); \
  BAR(); \
  /* P3: read A[qm1] (8 rds), stage B(T+2)->buf h0, mfma q(1,1) */ \
  _Pragma("unroll") for (int i = 0; i < 4; ++i) { \
    a[i][0] = *(const bf16x8*)&As[(buf)*16384 + aR + (4+i)*1024 + sw0]; \
    a[i][1] = *(const bf16x8*)&As[(buf)*16384 + aR + (4+i)*1024 + sw1]; } \
  STAGE_B(buf, 0); \
  BAR(); \
  asm volatile("s_waitcnt lgkmcnt(0)" ::: "memory"); \
  __builtin_amdgcn_s_setprio(1); \
  _Pragma("unroll") for (int i = 0; i < 4; ++i) \
    _Pragma("unroll") for (int j = 0; j < 2; ++j) { \
      MFMA(acc[4+i][2+j], a[i][0], b1[j][0]); MFMA(acc[4+i][2+j], a[i][1], b1[j][1]); } \
  __builtin_amdgcn_s_setprio(0); \
  BAR(); \
  /* P4: no reads, stage B h1, mfma q(1,0), counted vmcnt before close */ \
  STAGE_B(buf, 1); kB += 64; if (kB >= K) kB = 0; \
  BAR(); \
  __builtin_amdgcn_s_setprio(1); \
  _Pragma("unroll") for (int i = 0; i < 4; ++i) \
    _Pragma("unroll") for (int j = 0; j < 2; ++j) { \
      MFMA(acc[4+i][j], a[i][0], b0[j][0]); MFMA(acc[4+i][j], a[i][1], b0[j][1]); } \
  __builtin_amdgcn_s_setprio(0); \
  asm volatile("s_waitcnt vmcnt(4)" ::: "memory"); \
  BAR(); \
} while (0)

    const int NIT = K >> 7;  // 2 tiles (128 k) per iteration
    for (int it = 0; it < NIT; ++it) {
        PHASES(0, 1);   // tile 2it   in buf0; stages A->buf1, B(T+2)->buf0
        PHASES(1, 0);   // tile 2it+1 in buf1; stages A->buf0, B(T+3)->buf1
    }

    asm volatile("s_waitcnt vmcnt(0)" ::: "memory");  // drain tail DMA

    // epilogue: C/D layout col = lane&15, row = quad*4 + reg (m89-verified)
    const int mBase = m0 + wm * 128;
    const int nBase = nbase + n0 + wn * 64;
    #pragma unroll
    for (int i = 0; i < 8; ++i) {
        const int mrow = mBase + i * 16 + quad * 4;
        #pragma unroll
        for (int j = 0; j < 4; ++j) {
            const int ncol = nBase + j * 16 + l16;
            #pragma unroll
            for (int r = 0; r < 4; ++r)
                C[(size_t)(mrow + r) * N + ncol] = acc[i][j][r];
        }
    }
#undef STAGE_A
#undef STAGE_B
#undef PHASES
}

extern "C" void kernel_launch(void* const* d_in, const int* in_sizes, int n_in,
                              void* d_out, int out_size, void* d_ws, size_t ws_size,
                              hipStream_t stream)
{
    const float* x     = (const float*)d_in[0];   // fp32 [M,K]
    const int*   q     = (const int*)d_in[1];     // [K,N]
    const int*   meta  = (const int*)d_in[2];     // [K/4,N]
    const float* scale = (const float*)d_in[3];   // fp32 [K/128,N]
    float*       out   = (float*)d_out;           // fp32 [M,N]

    // M*K = s0, K*N = s1, M*N = out_size  =>  K = sqrt(s0*s1/out)
    const double s0 = (double)in_sizes[0];
    const double s1 = (double)in_sizes[1];
    const int K = (int)llround(sqrt(s0 * s1 / (double)out_size));
    const int M = in_sizes[0] / K;
    const int N = in_sizes[1] / K;

    // ws layout: [ x_bf16 : M*K*2 bytes ][ wt chunk : NC*K*2 bytes ]
    unsigned short* xb = (unsigned short*)d_ws;
    const size_t xb_bytes = (size_t)M * (size_t)K * 2;
    unsigned short* wt = (unsigned short*)((char*)d_ws + xb_bytes);
    const size_t wt_avail = ws_size > xb_bytes ? ws_size - xb_bytes : 0;

    const long long total = (long long)M * K;
    convert_x<<<dim3((unsigned)((total / 8 + 255) / 256)), dim3(256), 0, stream>>>(
        x, xb, total);

    long long maxrows = (long long)(wt_avail / ((size_t)K * 2));
    int NC = (int)((maxrows / 256) * 256);   // gemm256 needs n-chunk % 256 == 0
    if (NC > N) NC = N;
    if (NC < 256) NC = 256;  // requires ws_size >= xb + 2 MiB

    for (int nbase = 0; nbase < N; nbase += NC) {
        const int nc = (N - nbase) < NC ? (N - nbase) : NC;
        dim3 g1(K / 64, nc / 64);
        dequant_wt<<<g1, dim3(256), 0, stream>>>(q, meta, scale, wt, K, N, nbase);
        dim3 g2(nc / 256, M / 256);
        gemm256<<<g2, dim3(512), 0, stream>>>(xb, wt, out, M, N, K, nbase);
    }
}

// Round 2
// 560.929 us; speedup vs baseline: 1.0212x; 1.0212x over previous
//
#include <hip/hip_runtime.h>
#include <cmath>

// ---------------------------------------------------------------------------
// Problem: out = x @ dequant(qweight, meta, scale)
//   x      : fp32 [M,K]  (reference fp16 realized as fp32 on device)
//   qweight: int32 [K,N] in [0,16);  meta: int32 [K/4,N] in [0,6)
//   scale  : fp32 [K/128,N];  out: fp32 [M,N]
// Pipeline: convert x->bf16, dequant W -> bf16 Wt[NC][K] (chunked), then GEMM.
// R7: R6's 8-phase 256^2 GEMM measured 500 TF with FETCH=558MB (8x ideal):
// n-major + mod-8 XCD swizzle gave each XCD 2 m-panels x ALL n-panels ->
// B working set 32MB >> 4MB L2 -> B refetched 16x; pipeline stalls at the
// 2 TB/s L2-fill rate (MfmaUtil 42%, issue-occupancy 20%, 0 bank conflicts).
// Fix: (a) L2-rectangle grid mapping: 8 rects of (gy/2)x(gx/4), XCD=bid%8
// owns one, n-fastest walk -> 12 panel-fetches/XCD = ~210MB total.
// (b) Rebalanced phases: all A-stages in P1 (3-phase slack to vmcnt(4)),
// b0-next ds_reads moved to P4 behind vmcnt(6) (5-phase slack for B).
// ---------------------------------------------------------------------------

typedef __attribute__((ext_vector_type(8))) short bf16x8;
typedef __attribute__((ext_vector_type(4))) float f32x4;

__device__ inline unsigned short f2bf(float f) {
    union { float f; unsigned u; } v; v.f = f;
    unsigned r = (v.u + 0x7FFFu + ((v.u >> 16) & 1u)) >> 16;  // RNE
    return (unsigned short)r;
}

// ---------------------------------------------------------------------------
// Kernel 0: x fp32 -> bf16, 8 elements/thread, fully coalesced. (unchanged)
// ---------------------------------------------------------------------------
__global__ __launch_bounds__(256) void convert_x(
    const float* __restrict__ x, unsigned short* __restrict__ xb, long long total)
{
    const long long base = ((long long)blockIdx.x * 256 + threadIdx.x) * 8;
    if (base + 8 > total) return;
    const float4 a = *reinterpret_cast<const float4*>(x + base);
    const float4 b = *reinterpret_cast<const float4*>(x + base + 4);
    uint4 o;
    o.x = (unsigned)f2bf(a.x) | ((unsigned)f2bf(a.y) << 16);
    o.y = (unsigned)f2bf(a.z) | ((unsigned)f2bf(a.w) << 16);
    o.z = (unsigned)f2bf(b.x) | ((unsigned)f2bf(b.y) << 16);
    o.w = (unsigned)f2bf(b.z) | ((unsigned)f2bf(b.w) << 16);
    *reinterpret_cast<uint4*>(xb + base) = o;
}

// ---------------------------------------------------------------------------
// Kernel 1: dequant + transpose one N-chunk. Tile = 64(k) x 64(n). (unchanged)
// Pattern LUT nibbles: [1100]->3 [1010]->5 [1001]->9 [0110]->6 [0101]->A
// [0011]->C  => 0xCA6953
// ---------------------------------------------------------------------------
__global__ __launch_bounds__(256) void dequant_wt(
    const int* __restrict__ q, const int* __restrict__ meta,
    const float* __restrict__ scale,
    unsigned short* __restrict__ wt,   // [NC, K] chunk-local, bf16
    int K, int N, int nbase)
{
    __shared__ __align__(16) unsigned short lds[64 * 68];  // [n][k], stride 68
    const int t  = threadIdx.x;
    const int n  = t & 63;
    const int kc = t >> 6;
    const int k0 = blockIdx.x * 64;
    const int nl0 = blockIdx.y * 64;
    const int ng = nbase + nl0 + n;
    const int g = k0 >> 7;
    const float sc = scale[(size_t)g * N + ng];
    const unsigned lut = 0xCA6953u;

    #pragma unroll
    for (int p = 0; p < 4; ++p) {
        const int kl = p * 16 + kc * 4;
        const int kg = k0 + kl;
        const int mv = meta[(size_t)(kg >> 2) * N + ng];
        const unsigned pat = (lut >> (mv * 4)) & 0xFu;
        unsigned short w[4];
        #pragma unroll
        for (int j = 0; j < 4; ++j) {
            const int qv = q[(size_t)(kg + j) * N + ng];
            const float wf = ((pat >> j) & 1u) ? (float)(qv - 8) * sc : 0.0f;
            w[j] = f2bf(wf);
        }
        uint2 pk;
        pk.x = (unsigned)w[0] | ((unsigned)w[1] << 16);
        pk.y = (unsigned)w[2] | ((unsigned)w[3] << 16);
        *reinterpret_cast<uint2*>(&lds[n * 68 + kl]) = pk;
    }
    __syncthreads();
    #pragma unroll
    for (int p = 0; p < 2; ++p) {
        const int idx = p * 256 + t;
        const int nr  = idx >> 3;
        const int ch  = idx & 7;
        const uint2 lo = *reinterpret_cast<const uint2*>(&lds[nr * 68 + ch * 8]);
        const uint2 hi = *reinterpret_cast<const uint2*>(&lds[nr * 68 + ch * 8 + 4]);
        uint4 vv; vv.x = lo.x; vv.y = lo.y; vv.z = hi.x; vv.w = hi.y;
        *reinterpret_cast<uint4*>(&wt[(size_t)(nl0 + nr) * K + k0 + ch * 8]) = vv;
    }
}

// ---------------------------------------------------------------------------
// Kernel 2: 256x256 8-phase GEMM. C[:, nbase+..] = A[M,K] * Bt[NC,K]^T.
// 512 thr = 8 waves (2M x 4N); per-wave 128x64 out; BK=64; 128 KiB LDS.
// LDS swizzle: chunk' = c ^ (row-ish), DMA dest linear + pre-swizzled global
// source; ds_read applies same XOR -> 0 bank conflicts (R6-verified).
// Phase schedule per K-tile (ds_reads 8/4/8/4, 16 MFMA each):
//   P1: read a[qm0]; stage A(T+1)->obuf (4 GLDS);        mfma q(0,0)
//   P2: read b1;                                          mfma q(0,1)
//   P3: read a[qm1]; stage B(T+2)h0->buf (2 GLDS);        mfma q(1,1)
//   P4: vmcnt(6); read b0next from obuf; stage B h1;      mfma q(1,0)
//       vmcnt(4) at close.
// Slack: A(T+1) issued P1, waited P4-close (~3 phases); B(T+1) issued
// prev-group P3/P4, waited next-group P4-start vmcnt(6) (~5 phases).
// ---------------------------------------------------------------------------
#define BAR() do { asm volatile("" ::: "memory"); \
                   __builtin_amdgcn_s_barrier(); \
                   asm volatile("" ::: "memory"); } while (0)

#define GLDS(g, s) __builtin_amdgcn_global_load_lds( \
    (const __attribute__((address_space(1))) void*)(g), \
    (__attribute__((address_space(3))) void*)(s), 16, 0, 0)

#define MFMA(d, x, y) d = __builtin_amdgcn_mfma_f32_16x16x32_bf16(x, y, d, 0, 0, 0)

__global__ __launch_bounds__(512, 2) void gemm256(
    const unsigned short* __restrict__ A,   // bf16 [M,K]
    const unsigned short* __restrict__ Bt,  // bf16 [NC,K] chunk-local
    float* __restrict__ C,                  // fp32 [M,N]
    int M, int N, int K, int nbase)
{
    __shared__ __align__(16) unsigned short As[32768];  // 2buf x 2half x 128 x 64
    __shared__ __align__(16) unsigned short Bs[32768];

    const int t    = threadIdx.x;
    const int w    = t >> 6;
    const int lane = t & 63;
    const int wm   = w >> 2;        // 0..1  (M dir)
    const int wn   = w & 3;         // 0..3  (N dir)
    const int l16  = lane & 15;
    const int quad = lane >> 4;

    // --- L2-rectangle grid mapping ------------------------------------------
    // HW dispatches orig-bid round-robin: XCD = bid % 8. Give each XCD a
    // contiguous (gy/2) x (gx/4) rectangle of the block grid, walked
    // n-fastest. Per-XCD panel fetches: gy/2 A-panels + gx/4 B-panels.
    const int gx = gridDim.x, gy = gridDim.y;
    int bid = blockIdx.y * gx + blockIdx.x;
    const int nwg = gx * gy;
    int m0, n0;
    if ((nwg & 7) == 0 && (gy & 1) == 0 && (gx & 3) == 0) {
        const int xcd = bid & 7;
        const int idx = bid >> 3;          // 0 .. nwg/8-1 == (gy/2)*(gx/4)-1
        const int cpr = gx >> 2;           // cols per rect
        const int lr  = idx / cpr;
        const int lc  = idx - lr * cpr;
        m0 = ((xcd >> 2) * (gy >> 1) + lr) * 256;
        n0 = ((xcd & 3) * cpr + lc) * 256;
    } else {
        // bijective mod-8 fallback (m204)
        int b2 = bid;
        if (nwg >= 8) {
            const int q8 = nwg >> 3, r8 = nwg & 7;
            const int xcd = bid & 7, off = bid >> 3;
            b2 = (xcd < r8 ? xcd * (q8 + 1) : r8 * (q8 + 1) + (xcd - r8) * q8) + off;
        }
        n0 = (b2 % gx) * 256;
        m0 = (b2 / gx) * 256;
    }

    // staging source bases (pre-swizzled chunk within each 128B row)
    const int    csrc = ((lane & 7) ^ ((lane >> 3) & 7)) * 8;  // elements
    const size_t aB = (size_t)(m0 + w * 8 + (lane >> 3)) * K + csrc;
    const size_t bB = (size_t)(n0 + w * 8 + (lane >> 3)) * K + csrc;
    const size_t J  = (size_t)64 * K;    // issue-1 row offset
    const size_t H  = (size_t)128 * K;   // half row offset
    const int sdst  = w * 512;           // wave-uniform LDS dest (ushort idx)

    // ds_read bases (ushort idx). chunk'(kk) = (kk*4+quad)^(lane&7)
    const int sw0 = ((quad ^ (lane & 7)) * 8);
    const int sw1 = (((4 + quad) ^ (lane & 7)) * 8);
    const int aR  = wm * 8192 + l16 * 64;
    const int bR  = (wn >> 1) * 8192 + ((wn & 1) * 64 + l16) * 64;

    int kA = 0, kB = 0;  // k element offset of next tile to stage

#define STAGE_A(buf, h) do { \
    GLDS(A + aB + (size_t)(h) * H + kA, &As[(buf)*16384 + (h)*8192 + sdst]); \
    GLDS(A + aB + (size_t)(h) * H + J + kA, &As[(buf)*16384 + (h)*8192 + 4096 + sdst]); \
  } while (0)
#define STAGE_B(buf, h) do { \
    GLDS(Bt + bB + (size_t)(h) * H + kB, &Bs[(buf)*16384 + (h)*8192 + sdst]); \
    GLDS(Bt + bB + (size_t)(h) * H + J + kB, &Bs[(buf)*16384 + (h)*8192 + 4096 + sdst]); \
  } while (0)

    f32x4 acc[8][4];
    #pragma unroll
    for (int i = 0; i < 8; ++i)
        #pragma unroll
        for (int j = 0; j < 4; ++j)
            acc[i][j] = (f32x4){0.f, 0.f, 0.f, 0.f};

    // prologue: T0.B -> buf0, T0.A -> buf0, T1.B -> buf1 (12 GLDS)
    STAGE_B(0, 0); STAGE_B(0, 1); kB += 64;
    STAGE_A(0, 0); STAGE_A(0, 1); kA += 64;
    STAGE_B(1, 0); STAGE_B(1, 1); kB += 64;
    asm volatile("s_waitcnt vmcnt(4)" ::: "memory");  // T0 landed; B(T1) in flight
    BAR();

    bf16x8 a[4][2], bA_[2][2], bB_[2][2];

    // preload b0 of tile 0 from buf0
    #pragma unroll
    for (int j = 0; j < 2; ++j) {
        bA_[j][0] = *(const bf16x8*)&Bs[bR + j * 1024 + sw0];
        bA_[j][1] = *(const bf16x8*)&Bs[bR + j * 1024 + sw1];
    }

    // 4 phases per K-tile. bcur = b0 of tile T (preloaded); bnxt receives
    // b0 of tile T+1 (read in P4 from obuf behind vmcnt(6)).
#define PHASES(buf, obuf, bcur, bnxt) do { \
  /* P1: read a[qm0] (8 rds), stage A(T+1)->obuf (4 GLDS), mfma q(0,0) */ \
  _Pragma("unroll") for (int i = 0; i < 4; ++i) { \
    a[i][0] = *(const bf16x8*)&As[(buf)*16384 + aR + i*1024 + sw0]; \
    a[i][1] = *(const bf16x8*)&As[(buf)*16384 + aR + i*1024 + sw1]; } \
  STAGE_A(obuf, 0); STAGE_A(obuf, 1); kA += 64; if (kA >= K) kA = 0; \
  BAR(); \
  asm volatile("s_waitcnt lgkmcnt(0)" ::: "memory"); \
  __builtin_amdgcn_s_setprio(1); \
  _Pragma("unroll") for (int i = 0; i < 4; ++i) \
    _Pragma("unroll") for (int j = 0; j < 2; ++j) { \
      MFMA(acc[i][j], a[i][0], bcur[j][0]); MFMA(acc[i][j], a[i][1], bcur[j][1]); } \
  __builtin_amdgcn_s_setprio(0); \
  BAR(); \
  /* P2: read b1 (4 rds), mfma q(0,1) */ \
  _Pragma("unroll") for (int j = 0; j < 2; ++j) { \
    bnxt[j][0] = *(const bf16x8*)&Bs[(buf)*16384 + bR + (2+j)*1024 + sw0]; \
    bnxt[j][1] = *(const bf16x8*)&Bs[(buf)*16384 + bR + (2+j)*1024 + sw1]; } \
  BAR(); \
  asm volatile("s_waitcnt lgkmcnt(0)" ::: "memory"); \
  __builtin_amdgcn_s_setprio(1); \
  _Pragma("unroll") for (int i = 0; i < 4; ++i) \
    _Pragma("unroll") for (int j = 0; j < 2; ++j) { \
      MFMA(acc[i][2+j], a[i][0], bnxt[j][0]); MFMA(acc[i][2+j], a[i][1], bnxt[j][1]); } \
  __builtin_amdgcn_s_setprio(0); \
  BAR(); \
  /* P3: read a[qm1] (8 rds), stage B(T+2)h0->buf, mfma q(1,1) */ \
  _Pragma("unroll") for (int i = 0; i < 4; ++i) { \
    a[i][0] = *(const bf16x8*)&As[(buf)*16384 + aR + (4+i)*1024 + sw0]; \
    a[i][1] = *(const bf16x8*)&As[(buf)*16384 + aR + (4+i)*1024 + sw1]; } \
  STAGE_B(buf, 0); \
  BAR(); \
  asm volatile("s_waitcnt lgkmcnt(0)" ::: "memory"); \
  __builtin_amdgcn_s_setprio(1); \
  _Pragma("unroll") for (int i = 0; i < 4; ++i) \
    _Pragma("unroll") for (int j = 0; j < 2; ++j) { \
      MFMA(acc[4+i][2+j], a[i][0], bnxt[j][0]); MFMA(acc[4+i][2+j], a[i][1], bnxt[j][1]); } \
  __builtin_amdgcn_s_setprio(0); \
  BAR(); \
  /* P4: vmcnt(6) [B(T+1) landed], read b0next from obuf (4 rds), */ \
  /* stage B(T+2)h1->buf, mfma q(1,0) with bcur, vmcnt(4) at close */ \
  asm volatile("s_waitcnt vmcnt(6)" ::: "memory"); \
  _Pragma("unroll") for (int j = 0; j < 2; ++j) { \
    bnxt[j][0] = *(const bf16x8*)&Bs[(obuf)*16384 + bR + j*1024 + sw0]; \
    bnxt[j][1] = *(const bf16x8*)&Bs[(obuf)*16384 + bR + j*1024 + sw1]; } \
  STAGE_B(buf, 1); kB += 64; if (kB >= K) kB = 0; \
  BAR(); \
  asm volatile("s_waitcnt lgkmcnt(0)" ::: "memory"); \
  __builtin_amdgcn_s_setprio(1); \
  _Pragma("unroll") for (int i = 0; i < 4; ++i) \
    _Pragma("unroll") for (int j = 0; j < 2; ++j) { \
      MFMA(acc[4+i][j], a[i][0], bcur[j][0]); MFMA(acc[4+i][j], a[i][1], bcur[j][1]); } \
  __builtin_amdgcn_s_setprio(0); \
  asm volatile("s_waitcnt vmcnt(4)" ::: "memory"); \
  BAR(); \
} while (0)

    const int NIT = K >> 7;  // 2 K-tiles (128 k) per iteration
    for (int it = 0; it < NIT; ++it) {
        PHASES(0, 1, bA_, bB_);   // tile 2it   in buf0
        PHASES(1, 0, bB_, bA_);   // tile 2it+1 in buf1
    }

    asm volatile("s_waitcnt vmcnt(0)" ::: "memory");  // drain tail DMA

    // epilogue: C/D layout col = lane&15, row = quad*4 + reg (m89-verified)
    const int mBase = m0 + wm * 128;
    const int nBase = nbase + n0 + wn * 64;
    #pragma unroll
    for (int i = 0; i < 8; ++i) {
        const int mrow = mBase + i * 16 + quad * 4;
        #pragma unroll
        for (int j = 0; j < 4; ++j) {
            const int ncol = nBase + j * 16 + l16;
            #pragma unroll
            for (int r = 0; r < 4; ++r)
                C[(size_t)(mrow + r) * N + ncol] = acc[i][j][r];
        }
    }
#undef STAGE_A
#undef STAGE_B
#undef PHASES
}

extern "C" void kernel_launch(void* const* d_in, const int* in_sizes, int n_in,
                              void* d_out, int out_size, void* d_ws, size_t ws_size,
                              hipStream_t stream)
{
    const float* x     = (const float*)d_in[0];   // fp32 [M,K]
    const int*   q     = (const int*)d_in[1];     // [K,N]
    const int*   meta  = (const int*)d_in[2];     // [K/4,N]
    const float* scale = (const float*)d_in[3];   // fp32 [K/128,N]
    float*       out   = (float*)d_out;           // fp32 [M,N]

    // M*K = s0, K*N = s1, M*N = out_size  =>  K = sqrt(s0*s1/out)
    const double s0 = (double)in_sizes[0];
    const double s1 = (double)in_sizes[1];
    const int K = (int)llround(sqrt(s0 * s1 / (double)out_size));
    const int M = in_sizes[0] / K;
    const int N = in_sizes[1] / K;

    // ws layout: [ x_bf16 : M*K*2 bytes ][ wt chunk : NC*K*2 bytes ]
    unsigned short* xb = (unsigned short*)d_ws;
    const size_t xb_bytes = (size_t)M * (size_t)K * 2;
    unsigned short* wt = (unsigned short*)((char*)d_ws + xb_bytes);
    const size_t wt_avail = ws_size > xb_bytes ? ws_size - xb_bytes : 0;

    const long long total = (long long)M * K;
    convert_x<<<dim3((unsigned)((total / 8 + 255) / 256)), dim3(256), 0, stream>>>(
        x, xb, total);

    long long maxrows = (long long)(wt_avail / ((size_t)K * 2));
    int NC = (int)((maxrows / 256) * 256);   // gemm256 needs n-chunk % 256 == 0
    if (NC > N) NC = N;
    if (NC < 256) NC = 256;  // requires ws_size >= xb + 2 MiB

    for (int nbase = 0; nbase < N; nbase += NC) {
        const int nc = (N - nbase) < NC ? (N - nbase) : NC;
        dim3 g1(K / 64, nc / 64);
        dequant_wt<<<g1, dim3(256), 0, stream>>>(q, meta, scale, wt, K, N, nbase);
        dim3 g2(nc / 256, M / 256);
        gemm256<<<g2, dim3(512), 0, stream>>>(xb, wt, out, M, N, K, nbase);
    }
}

// Round 3
// 553.406 us; speedup vs baseline: 1.0351x; 1.0136x over previous
//
#include <hip/hip_runtime.h>
#include <cmath>

// ---------------------------------------------------------------------------
// Problem: out = x @ dequant(qweight, meta, scale)
//   x      : fp32 [M,K]  (reference fp16 realized as fp32 on device)
//   qweight: int32 [K,N] in [0,16);  meta: int32 [K/4,N] in [0,6)
//   scale  : fp32 [K/128,N];  out: fp32 [M,N]
// Pipeline: convert x->bf16, dequant W -> bf16 Wt[N][K], single 256^2 8-phase
// GEMM (NC=8192 fits ws). R8 findings: R7 cut FETCH 558->202MB but dur flat
// (278us, 988 TF, MfmaUtil 43) -> schedule-bound, not fill-rate. ~282us of
// wall is OUTSIDE the gemm (convert+dequant+overhead).
// R8 changes: (a) m201-canonical phases: exactly 2 GLDS/phase
// (A-h0/A-h1/B-h0/B-h1), reads 8/4/8/4, counted waits ONLY at phase closes:
// vmcnt(6)@P3-close (B(T+1) landed -> P4 b0next reads), vmcnt(4)@P4-close
// (A(T+1) landed). No mid-phase stalls. (b) dequant vectorized: int4 q loads,
// int4 meta, float4 scale (6 vec loads/thread vs 21 scalar).
// ---------------------------------------------------------------------------

typedef __attribute__((ext_vector_type(8))) short bf16x8;
typedef __attribute__((ext_vector_type(4))) float f32x4;

__device__ inline unsigned short f2bf(float f) {
    union { float f; unsigned u; } v; v.f = f;
    unsigned r = (v.u + 0x7FFFu + ((v.u >> 16) & 1u)) >> 16;  // RNE
    return (unsigned short)r;
}

// ---------------------------------------------------------------------------
// Kernel 0: x fp32 -> bf16, 8 elements/thread, fully coalesced. (unchanged)
// ---------------------------------------------------------------------------
__global__ __launch_bounds__(256) void convert_x(
    const float* __restrict__ x, unsigned short* __restrict__ xb, long long total)
{
    const long long base = ((long long)blockIdx.x * 256 + threadIdx.x) * 8;
    if (base + 8 > total) return;
    const float4 a = *reinterpret_cast<const float4*>(x + base);
    const float4 b = *reinterpret_cast<const float4*>(x + base + 4);
    uint4 o;
    o.x = (unsigned)f2bf(a.x) | ((unsigned)f2bf(a.y) << 16);
    o.y = (unsigned)f2bf(a.z) | ((unsigned)f2bf(a.w) << 16);
    o.z = (unsigned)f2bf(b.x) | ((unsigned)f2bf(b.y) << 16);
    o.w = (unsigned)f2bf(b.z) | ((unsigned)f2bf(b.w) << 16);
    *reinterpret_cast<uint4*>(xb + base) = o;
}

// ---------------------------------------------------------------------------
// Kernel 1: dequant + transpose one N-chunk. Tile = 64(k) x 64(n).
// R8: vectorized. Thread (t&15)*4 = n-group of 4, t>>4 = k-group of 4.
// Loads: 4x int4 (q rows), 1x int4 (meta row), 1x float4 (scale).
// Pattern LUT nibbles: [1100]->3 [1010]->5 [1001]->9 [0110]->6 [0101]->A
// [0011]->C  => 0xCA6953
// ---------------------------------------------------------------------------
__global__ __launch_bounds__(256) void dequant_wt(
    const int* __restrict__ q, const int* __restrict__ meta,
    const float* __restrict__ scale,
    unsigned short* __restrict__ wt,   // [NC, K] chunk-local, bf16
    int K, int N, int nbase)
{
    __shared__ __align__(16) unsigned short lds[64 * 68];  // [n][k], stride 68
    const int t   = threadIdx.x;
    const int n4  = (t & 15) * 4;      // 4 consecutive n per thread
    const int kc  = t >> 4;            // 0..15, 4 k each
    const int kl  = kc * 4;
    const int k0  = blockIdx.x * 64;
    const int nl0 = blockIdx.y * 64;
    const int ng  = nbase + nl0 + n4;
    const int kg  = k0 + kl;
    const int g   = k0 >> 7;           // 64-row k-tile within one 128 group
    const unsigned lut = 0xCA6953u;

    const float4 sc4 = *reinterpret_cast<const float4*>(&scale[(size_t)g * N + ng]);
    const int4   mv4 = *reinterpret_cast<const int4*>(&meta[(size_t)(kg >> 2) * N + ng]);
    int4 q4[4];
    #pragma unroll
    for (int j = 0; j < 4; ++j)
        q4[j] = *reinterpret_cast<const int4*>(&q[(size_t)(kg + j) * N + ng]);

    #pragma unroll
    for (int nn = 0; nn < 4; ++nn) {
        const int mv = ((const int*)&mv4)[nn];
        const unsigned pat = (lut >> (mv * 4)) & 0xFu;
        const float sc = ((const float*)&sc4)[nn];
        unsigned short w[4];
        #pragma unroll
        for (int j = 0; j < 4; ++j) {
            const int qv = ((const int*)&q4[j])[nn];
            const float wf = ((pat >> j) & 1u) ? (float)(qv - 8) * sc : 0.0f;
            w[j] = f2bf(wf);
        }
        uint2 pk;
        pk.x = (unsigned)w[0] | ((unsigned)w[1] << 16);
        pk.y = (unsigned)w[2] | ((unsigned)w[3] << 16);
        *reinterpret_cast<uint2*>(&lds[(n4 + nn) * 68 + kl]) = pk;
    }
    __syncthreads();
    #pragma unroll
    for (int p = 0; p < 2; ++p) {
        const int idx = p * 256 + t;
        const int nr  = idx >> 3;
        const int ch  = idx & 7;
        const uint2 lo = *reinterpret_cast<const uint2*>(&lds[nr * 68 + ch * 8]);
        const uint2 hi = *reinterpret_cast<const uint2*>(&lds[nr * 68 + ch * 8 + 4]);
        uint4 vv; vv.x = lo.x; vv.y = lo.y; vv.z = hi.x; vv.w = hi.y;
        *reinterpret_cast<uint4*>(&wt[(size_t)(nl0 + nr) * K + k0 + ch * 8]) = vv;
    }
}

// ---------------------------------------------------------------------------
// Kernel 2: 256x256 8-phase GEMM. C[:, nbase+..] = A[M,K] * Bt[NC,K]^T.
// 512 thr = 8 waves (2M x 4N); per-wave 128x64 out; BK=64; 128 KiB LDS.
// Chunk-XOR LDS swizzle (0 bank conflicts, R6-verified). L2-rectangle grid
// mapping (FETCH 558->202MB, R7-verified).
// Per K-tile T (4 phases, 16 MFMA each; b0 double-buffered across tiles):
//   P1: 8 a-rds(qm0);        STAGE A(T+1)h0->obuf;  mfma q(0,0) w/ bcur
//   P2: 4 b1-rds;            STAGE A(T+1)h1->obuf;  mfma q(0,1) w/ bnxt
//   P3: 8 a-rds(qm1);        STAGE B(T+2)h0->buf;   mfma q(1,1) w/ bnxt
//       close: vmcnt(6)  [completes B(T+1): 4 older of 10 outstanding]
//   P4: 4 b0next-rds (obuf); STAGE B(T+2)h1->buf;   mfma q(1,0) w/ bcur
//       close: vmcnt(4)  [completes A(T+1)]
// ---------------------------------------------------------------------------
#define BAR() do { asm volatile("" ::: "memory"); \
                   __builtin_amdgcn_s_barrier(); \
                   asm volatile("" ::: "memory"); } while (0)

#define GLDS(g, s) __builtin_amdgcn_global_load_lds( \
    (const __attribute__((address_space(1))) void*)(g), \
    (__attribute__((address_space(3))) void*)(s), 16, 0, 0)

#define MFMA(d, x, y) d = __builtin_amdgcn_mfma_f32_16x16x32_bf16(x, y, d, 0, 0, 0)

__global__ __launch_bounds__(512, 2) void gemm256(
    const unsigned short* __restrict__ A,   // bf16 [M,K]
    const unsigned short* __restrict__ Bt,  // bf16 [NC,K] chunk-local
    float* __restrict__ C,                  // fp32 [M,N]
    int M, int N, int K, int nbase)
{
    __shared__ __align__(16) unsigned short As[32768];  // 2buf x 2half x 128 x 64
    __shared__ __align__(16) unsigned short Bs[32768];

    const int t    = threadIdx.x;
    const int w    = t >> 6;
    const int lane = t & 63;
    const int wm   = w >> 2;        // 0..1  (M dir)
    const int wn   = w & 3;         // 0..3  (N dir)
    const int l16  = lane & 15;
    const int quad = lane >> 4;

    // --- L2-rectangle grid mapping (R7-verified) ---------------------------
    const int gx = gridDim.x, gy = gridDim.y;
    int bid = blockIdx.y * gx + blockIdx.x;
    const int nwg = gx * gy;
    int m0, n0;
    if ((nwg & 7) == 0 && (gy & 1) == 0 && (gx & 3) == 0) {
        const int xcd = bid & 7;
        const int idx = bid >> 3;
        const int cpr = gx >> 2;
        const int lr  = idx / cpr;
        const int lc  = idx - lr * cpr;
        m0 = ((xcd >> 2) * (gy >> 1) + lr) * 256;
        n0 = ((xcd & 3) * cpr + lc) * 256;
    } else {
        int b2 = bid;
        if (nwg >= 8) {
            const int q8 = nwg >> 3, r8 = nwg & 7;
            const int xcd = bid & 7, off = bid >> 3;
            b2 = (xcd < r8 ? xcd * (q8 + 1) : r8 * (q8 + 1) + (xcd - r8) * q8) + off;
        }
        n0 = (b2 % gx) * 256;
        m0 = (b2 / gx) * 256;
    }

    // staging source bases (pre-swizzled chunk within each 128B row)
    const int    csrc = ((lane & 7) ^ ((lane >> 3) & 7)) * 8;  // elements
    const size_t aB = (size_t)(m0 + w * 8 + (lane >> 3)) * K + csrc;
    const size_t bB = (size_t)(n0 + w * 8 + (lane >> 3)) * K + csrc;
    const size_t J  = (size_t)64 * K;    // issue-1 row offset
    const size_t H  = (size_t)128 * K;   // half row offset
    const int sdst  = w * 512;           // wave-uniform LDS dest (ushort idx)

    // ds_read bases (ushort idx). chunk'(kk) = (kk*4+quad)^(lane&7)
    const int sw0 = ((quad ^ (lane & 7)) * 8);
    const int sw1 = (((4 + quad) ^ (lane & 7)) * 8);
    const int aR  = wm * 8192 + l16 * 64;
    const int bR  = (wn >> 1) * 8192 + ((wn & 1) * 64 + l16) * 64;

    int kA = 0, kB = 0;  // k element offset of next tile to stage

#define STAGE_A(buf, h) do { \
    GLDS(A + aB + (size_t)(h) * H + kA, &As[(buf)*16384 + (h)*8192 + sdst]); \
    GLDS(A + aB + (size_t)(h) * H + J + kA, &As[(buf)*16384 + (h)*8192 + 4096 + sdst]); \
  } while (0)
#define STAGE_B(buf, h) do { \
    GLDS(Bt + bB + (size_t)(h) * H + kB, &Bs[(buf)*16384 + (h)*8192 + sdst]); \
    GLDS(Bt + bB + (size_t)(h) * H + J + kB, &Bs[(buf)*16384 + (h)*8192 + 4096 + sdst]); \
  } while (0)

    f32x4 acc[8][4];
    #pragma unroll
    for (int i = 0; i < 8; ++i)
        #pragma unroll
        for (int j = 0; j < 4; ++j)
            acc[i][j] = (f32x4){0.f, 0.f, 0.f, 0.f};

    // prologue: A(T0)->buf0, B(T0)->buf0, B(T1)->buf1 (12 GLDS).
    // vmcnt(4) completes A(T0)+B(T0); leftover B(T1)x4 == steady state.
    STAGE_A(0, 0); STAGE_A(0, 1); kA += 64;
    STAGE_B(0, 0); STAGE_B(0, 1); kB += 64;
    STAGE_B(1, 0); STAGE_B(1, 1); kB += 64;
    asm volatile("s_waitcnt vmcnt(4)" ::: "memory");
    BAR();

    bf16x8 a[4][2], bA_[2][2], bB_[2][2];

    // preload b0 of tile 0 from buf0
    #pragma unroll
    for (int j = 0; j < 2; ++j) {
        bA_[j][0] = *(const bf16x8*)&Bs[bR + j * 1024 + sw0];
        bA_[j][1] = *(const bf16x8*)&Bs[bR + j * 1024 + sw1];
    }

#define PHASES(buf, obuf, bcur, bnxt) do { \
  /* P1: 8 a-rds (qm0), STAGE A(T+1)h0 -> obuf, mfma q(0,0) w/ bcur */ \
  _Pragma("unroll") for (int i = 0; i < 4; ++i) { \
    a[i][0] = *(const bf16x8*)&As[(buf)*16384 + aR + i*1024 + sw0]; \
    a[i][1] = *(const bf16x8*)&As[(buf)*16384 + aR + i*1024 + sw1]; } \
  STAGE_A(obuf, 0); \
  BAR(); \
  asm volatile("s_waitcnt lgkmcnt(0)" ::: "memory"); \
  __builtin_amdgcn_s_setprio(1); \
  _Pragma("unroll") for (int i = 0; i < 4; ++i) \
    _Pragma("unroll") for (int j = 0; j < 2; ++j) { \
      MFMA(acc[i][j], a[i][0], bcur[j][0]); MFMA(acc[i][j], a[i][1], bcur[j][1]); } \
  __builtin_amdgcn_s_setprio(0); \
  BAR(); \
  /* P2: 4 b1-rds -> bnxt, STAGE A(T+1)h1 -> obuf, mfma q(0,1) */ \
  _Pragma("unroll") for (int j = 0; j < 2; ++j) { \
    bnxt[j][0] = *(const bf16x8*)&Bs[(buf)*16384 + bR + (2+j)*1024 + sw0]; \
    bnxt[j][1] = *(const bf16x8*)&Bs[(buf)*16384 + bR + (2+j)*1024 + sw1]; } \
  STAGE_A(obuf, 1); kA += 64; if (kA >= K) kA = 0; \
  BAR(); \
  asm volatile("s_waitcnt lgkmcnt(0)" ::: "memory"); \
  __builtin_amdgcn_s_setprio(1); \
  _Pragma("unroll") for (int i = 0; i < 4; ++i) \
    _Pragma("unroll") for (int j = 0; j < 2; ++j) { \
      MFMA(acc[i][2+j], a[i][0], bnxt[j][0]); MFMA(acc[i][2+j], a[i][1], bnxt[j][1]); } \
  __builtin_amdgcn_s_setprio(0); \
  BAR(); \
  /* P3: 8 a-rds (qm1), STAGE B(T+2)h0 -> buf, mfma q(1,1), vmcnt(6) close */ \
  _Pragma("unroll") for (int i = 0; i < 4; ++i) { \
    a[i][0] = *(const bf16x8*)&As[(buf)*16384 + aR + (4+i)*1024 + sw0]; \
    a[i][1] = *(const bf16x8*)&As[(buf)*16384 + aR + (4+i)*1024 + sw1]; } \
  STAGE_B(buf, 0); \
  BAR(); \
  asm volatile("s_waitcnt lgkmcnt(0)" ::: "memory"); \
  __builtin_amdgcn_s_setprio(1); \
  _Pragma("unroll") for (int i = 0; i < 4; ++i) \
    _Pragma("unroll") for (int j = 0; j < 2; ++j) { \
      MFMA(acc[4+i][2+j], a[i][0], bnxt[j][0]); MFMA(acc[4+i][2+j], a[i][1], bnxt[j][1]); } \
  __builtin_amdgcn_s_setprio(0); \
  asm volatile("s_waitcnt vmcnt(6)" ::: "memory"); \
  BAR(); \
  /* P4: 4 b0next-rds (obuf) -> bnxt, STAGE B(T+2)h1 -> buf, mfma q(1,0), */ \
  /*     vmcnt(4) close */ \
  _Pragma("unroll") for (int j = 0; j < 2; ++j) { \
    bnxt[j][0] = *(const bf16x8*)&Bs[(obuf)*16384 + bR + j*1024 + sw0]; \
    bnxt[j][1] = *(const bf16x8*)&Bs[(obuf)*16384 + bR + j*1024 + sw1]; } \
  STAGE_B(buf, 1); kB += 64; if (kB >= K) kB = 0; \
  BAR(); \
  asm volatile("s_waitcnt lgkmcnt(0)" ::: "memory"); \
  __builtin_amdgcn_s_setprio(1); \
  _Pragma("unroll") for (int i = 0; i < 4; ++i) \
    _Pragma("unroll") for (int j = 0; j < 2; ++j) { \
      MFMA(acc[4+i][j], a[i][0], bcur[j][0]); MFMA(acc[4+i][j], a[i][1], bcur[j][1]); } \
  __builtin_amdgcn_s_setprio(0); \
  asm volatile("s_waitcnt vmcnt(4)" ::: "memory"); \
  BAR(); \
} while (0)

    const int NIT = K >> 7;  // 2 K-tiles (128 k) per iteration
    for (int it = 0; it < NIT; ++it) {
        PHASES(0, 1, bA_, bB_);   // tile 2it   in buf0
        PHASES(1, 0, bB_, bA_);   // tile 2it+1 in buf1
    }

    asm volatile("s_waitcnt vmcnt(0)" ::: "memory");  // drain tail DMA

    // epilogue: C/D layout col = lane&15, row = quad*4 + reg (m89-verified)
    const int mBase = m0 + wm * 128;
    const int nBase = nbase + n0 + wn * 64;
    #pragma unroll
    for (int i = 0; i < 8; ++i) {
        const int mrow = mBase + i * 16 + quad * 4;
        #pragma unroll
        for (int j = 0; j < 4; ++j) {
            const int ncol = nBase + j * 16 + l16;
            #pragma unroll
            for (int r = 0; r < 4; ++r)
                C[(size_t)(mrow + r) * N + ncol] = acc[i][j][r];
        }
    }
#undef STAGE_A
#undef STAGE_B
#undef PHASES
}

extern "C" void kernel_launch(void* const* d_in, const int* in_sizes, int n_in,
                              void* d_out, int out_size, void* d_ws, size_t ws_size,
                              hipStream_t stream)
{
    const float* x     = (const float*)d_in[0];   // fp32 [M,K]
    const int*   q     = (const int*)d_in[1];     // [K,N]
    const int*   meta  = (const int*)d_in[2];     // [K/4,N]
    const float* scale = (const float*)d_in[3];   // fp32 [K/128,N]
    float*       out   = (float*)d_out;           // fp32 [M,N]

    // M*K = s0, K*N = s1, M*N = out_size  =>  K = sqrt(s0*s1/out)
    const double s0 = (double)in_sizes[0];
    const double s1 = (double)in_sizes[1];
    const int K = (int)llround(sqrt(s0 * s1 / (double)out_size));
    const int M = in_sizes[0] / K;
    const int N = in_sizes[1] / K;

    // ws layout: [ x_bf16 : M*K*2 bytes ][ wt chunk : NC*K*2 bytes ]
    unsigned short* xb = (unsigned short*)d_ws;
    const size_t xb_bytes = (size_t)M * (size_t)K * 2;
    unsigned short* wt = (unsigned short*)((char*)d_ws + xb_bytes);
    const size_t wt_avail = ws_size > xb_bytes ? ws_size - xb_bytes : 0;

    const long long total = (long long)M * K;
    convert_x<<<dim3((unsigned)((total / 8 + 255) / 256)), dim3(256), 0, stream>>>(
        x, xb, total);

    long long maxrows = (long long)(wt_avail / ((size_t)K * 2));
    int NC = (int)((maxrows / 256) * 256);   // gemm256 needs n-chunk % 256 == 0
    if (NC > N) NC = N;
    if (NC < 256) NC = 256;  // requires ws_size >= xb + 2 MiB

    for (int nbase = 0; nbase < N; nbase += NC) {
        const int nc = (N - nbase) < NC ? (N - nbase) : NC;
        dim3 g1(K / 64, nc / 64);
        dequant_wt<<<g1, dim3(256), 0, stream>>>(q, meta, scale, wt, K, N, nbase);
        dim3 g2(nc / 256, M / 256);
        gemm256<<<g2, dim3(512), 0, stream>>>(xb, wt, out, M, N, K, nbase);
    }
}